// Round 1
// baseline (440.840 us; speedup 1.0000x reference)
//
#include <hip/hip_runtime.h>

// ---------------------------------------------------------------------------
// network_49581102465567: 5-layer linear MLP with scalar codebook quantization
// after layer 2. All layers are LINEAR -> fold w1,w2 into Wa [1024x512] and
// w3,w4,w5 into Wc [512x512]. Per-call work: 9.7 GF fold + 25.8 GF main
// (vs 412 GF naive).
//
// All GEMMs in B^T form: C[m][n] = sum_k A[m][k] * Bt[n][k], bf16 MFMA
// 16x16x32, fp32 accum. 128x128 block tile, BK=32, 256 thr = 4 waves,
// each wave 4x4 16x16 sub-tiles.
// ---------------------------------------------------------------------------

typedef __bf16 v8bf __attribute__((ext_vector_type(8)));
typedef float  v4f  __attribute__((ext_vector_type(4)));

#define Bdim   16384
#define DIN    1024
#define DOUT   512
#define H1dim  4096
#define H3dim  2048
#define H4dim  2048

// ---- elementwise cast fp32 -> bf16, 4 elems/thread ----
__global__ void cast_bf16_kernel(const float* __restrict__ in,
                                 __bf16* __restrict__ out, int n4) {
  int i = blockIdx.x * blockDim.x + threadIdx.x;
  if (i >= n4) return;
  float4 v = reinterpret_cast<const float4*>(in)[i];
  unsigned h0 = __builtin_bit_cast(unsigned short, (__bf16)v.x);
  unsigned h1 = __builtin_bit_cast(unsigned short, (__bf16)v.y);
  unsigned h2 = __builtin_bit_cast(unsigned short, (__bf16)v.z);
  unsigned h3 = __builtin_bit_cast(unsigned short, (__bf16)v.w);
  uint2 o;
  o.x = h0 | (h1 << 16);
  o.y = h2 | (h3 << 16);
  reinterpret_cast<uint2*>(out)[i] = o;
}

// ---- transpose + cast: in fp32 [R][C] -> out bf16 [C][R] ----
__global__ void transpose_cast_kernel(const float* __restrict__ in,
                                      __bf16* __restrict__ out, int R, int C) {
  __shared__ float tile[32][33];  // +1 pad: conflict-free transpose
  const int c0 = blockIdx.x * 32, r0 = blockIdx.y * 32;
  const int t = threadIdx.x, tr = t >> 5, tc = t & 31;
#pragma unroll
  for (int i = 0; i < 4; ++i)
    tile[tr + i * 8][tc] = in[(size_t)(r0 + tr + i * 8) * C + (c0 + tc)];
  __syncthreads();
#pragma unroll
  for (int i = 0; i < 4; ++i)
    out[(size_t)(c0 + tr + i * 8) * R + (r0 + tc)] = (__bf16)tile[tc][tr + i * 8];
}

// ---- folded bias vectors ----
// ba[j] = dot(b1, w2[j,:]) + b2[j]            (K=4096)
__global__ void ba_kernel(const float* __restrict__ b1, const float* __restrict__ w2,
                          const float* __restrict__ b2, float* __restrict__ ba) {
  const int wave = threadIdx.x >> 6, lane = threadIdx.x & 63;
  const int j = blockIdx.x * 4 + wave;
  float s = 0.f;
  for (int k = lane; k < H1dim; k += 64) s += b1[k] * w2[(size_t)j * H1dim + k];
#pragma unroll
  for (int off = 32; off; off >>= 1) s += __shfl_xor(s, off, 64);
  if (lane == 0) ba[j] = s + b2[j];
}

// bc[j] = dot(b3, WtT[j,:]) + dot(b4, w5[j,:]) + b5[j]   (K=2048 each)
__global__ void bc_kernel(const float* __restrict__ b3, const __bf16* __restrict__ WtT,
                          const float* __restrict__ b4, const float* __restrict__ w5,
                          const float* __restrict__ b5, float* __restrict__ bc) {
  const int wave = threadIdx.x >> 6, lane = threadIdx.x & 63;
  const int j = blockIdx.x * 4 + wave;
  float s = 0.f;
  for (int k = lane; k < H4dim; k += 64)
    s += b3[k] * (float)WtT[(size_t)j * H4dim + k] + b4[k] * w5[(size_t)j * H4dim + k];
#pragma unroll
  for (int off = 32; off; off >>= 1) s += __shfl_xor(s, off, 64);
  if (lane == 0) bc[j] = s + b5[j];
}

// ---- B^T-form bf16 MFMA GEMM: C[m][n] = sum_k A[m][k]*Bt[n][k] (+epilogue)
enum { MODE_BF16 = 0, MODE_Q = 1, MODE_OUT = 2 };

template <int MODE>
__global__ __launch_bounds__(256, 2)
void gemm_bt_kernel(const __bf16* __restrict__ A, const __bf16* __restrict__ Bt,
                    void* __restrict__ Cout, const float* __restrict__ bias,
                    const float* __restrict__ codebook, int M, int N, int K) {
  __shared__ __bf16 As[128 * 32];
  __shared__ __bf16 Bs[128 * 32];
  __shared__ float cbs[256];

  const int t = threadIdx.x;
  const int m0 = blockIdx.x * 128;
  const int n0 = blockIdx.y * 128;
  if (MODE == MODE_Q) cbs[t] = codebook[t];  // covered by first __syncthreads

  const int lane = t & 63, wave = t >> 6;
  const int quad = lane >> 4, l15 = lane & 15;
  const int wm = (wave & 1) * 64, wn = (wave >> 1) * 64;

  v4f acc[4][4];
#pragma unroll
  for (int i = 0; i < 4; ++i)
#pragma unroll
    for (int j = 0; j < 4; ++j) acc[i][j] = (v4f){0.f, 0.f, 0.f, 0.f};

  for (int k0 = 0; k0 < K; k0 += 32) {
    // stage 128x32 bf16 tiles (8 KB each), 16B per thread per pass, 2 passes
#pragma unroll
    for (int p = 0; p < 2; ++p) {
      const int e = (p * 256 + t) * 8;      // element index in [128][32] tile
      const int r = e >> 5, c = e & 31;
      *(int4*)&As[e] = *(const int4*)&A[(size_t)(m0 + r) * K + (k0 + c)];
      *(int4*)&Bs[e] = *(const int4*)&Bt[(size_t)(n0 + r) * K + (k0 + c)];
    }
    __syncthreads();

    v8bf af[4], bfr[4];
#pragma unroll
    for (int i = 0; i < 4; ++i) {
      af[i]  = *(const v8bf*)&As[(wm + i * 16 + l15) * 32 + quad * 8];
      bfr[i] = *(const v8bf*)&Bs[(wn + i * 16 + l15) * 32 + quad * 8];
    }
#pragma unroll
    for (int i = 0; i < 4; ++i)
#pragma unroll
      for (int j = 0; j < 4; ++j)
        acc[i][j] = __builtin_amdgcn_mfma_f32_16x16x32_bf16(af[i], bfr[j], acc[i][j], 0, 0, 0);
    __syncthreads();
  }

  // epilogue: D row = quad*4+r (A's m), col = l15 (Bt's n)
#pragma unroll
  for (int i = 0; i < 4; ++i) {
#pragma unroll
    for (int j = 0; j < 4; ++j) {
#pragma unroll
      for (int r = 0; r < 4; ++r) {
        const int gm = m0 + wm + i * 16 + quad * 4 + r;
        const int gn = n0 + wn + j * 16 + l15;
        float v = acc[i][j][r];
        if constexpr (MODE == MODE_BF16) {
          ((__bf16*)Cout)[(size_t)gm * N + gn] = (__bf16)v;
        } else if constexpr (MODE == MODE_Q) {
          v += bias[gn];
          // nearest codeword, argmin-first tie-break (pick lower index on tie)
          int idx = 0;
#pragma unroll
          for (int s = 128; s > 0; s >>= 1) {
            const int u = idx + s;          // max reachable: 255, never OOB
            if (cbs[u] <= v) idx = u;
          }
          float best = cbs[idx];
          if (idx < 255) {
            const float c1 = cbs[idx + 1];
            if (!(v - best <= c1 - v)) best = c1;
          }
          ((__bf16*)Cout)[(size_t)gm * N + gn] = (__bf16)best;
        } else {  // MODE_OUT
          v += bias[gn];
          ((float*)Cout)[(size_t)gm * N + gn] = v;
        }
      }
    }
  }
}

extern "C" void kernel_launch(void* const* d_in, const int* in_sizes, int n_in,
                              void* d_out, int out_size, void* d_ws, size_t ws_size,
                              hipStream_t stream) {
  const float* x  = (const float*)d_in[0];
  const float* cb = (const float*)d_in[1];
  const float* w1 = (const float*)d_in[2];   // [4096,1024]
  const float* b1 = (const float*)d_in[3];
  const float* w2 = (const float*)d_in[4];   // [512,4096]
  const float* b2 = (const float*)d_in[5];
  const float* w3 = (const float*)d_in[6];   // [2048,512]
  const float* b3 = (const float*)d_in[7];
  const float* w4 = (const float*)d_in[8];   // [2048,2048]
  const float* b4 = (const float*)d_in[9];
  const float* w5 = (const float*)d_in[10];  // [512,2048]
  const float* b5 = (const float*)d_in[11];
  float* out = (float*)d_out;

  char* ws = (char*)d_ws;
  size_t off = 0;
  auto alloc = [&](size_t bytes) -> void* {
    void* p = ws + off;
    off = (off + bytes + 255) & ~(size_t)255;
    return p;
  };
  __bf16* x_bf  = (__bf16*)alloc((size_t)Bdim * DIN * 2);     // 33.5 MB
  __bf16* w1T   = (__bf16*)alloc((size_t)DIN * H1dim * 2);    // [1024][4096]
  __bf16* w2_bf = (__bf16*)alloc((size_t)DOUT * H1dim * 2);   // [512][4096]
  __bf16* w4T   = (__bf16*)alloc((size_t)H3dim * H4dim * 2);  // [2048][2048]
  __bf16* w3T   = (__bf16*)alloc((size_t)DOUT * H3dim * 2);   // [512][2048]
  __bf16* w5_bf = (__bf16*)alloc((size_t)DOUT * H4dim * 2);   // [512][2048]
  __bf16* WaT   = (__bf16*)alloc((size_t)DOUT * DIN * 2);     // [512][1024]
  __bf16* WtT   = (__bf16*)alloc((size_t)DOUT * H3dim * 2);   // [512][2048]
  __bf16* WcT   = (__bf16*)alloc((size_t)DOUT * DOUT * 2);    // [512][512]
  __bf16* q     = (__bf16*)alloc((size_t)Bdim * DOUT * 2);    // 16.8 MB
  float*  ba    = (float*)alloc(DOUT * 4);
  float*  bc    = (float*)alloc(DOUT * 4);

  // casts
  cast_bf16_kernel<<<(Bdim * DIN / 4 + 255) / 256, 256, 0, stream>>>(x, x_bf, Bdim * DIN / 4);
  cast_bf16_kernel<<<(DOUT * H1dim / 4 + 255) / 256, 256, 0, stream>>>(w2, w2_bf, DOUT * H1dim / 4);
  cast_bf16_kernel<<<(DOUT * H4dim / 4 + 255) / 256, 256, 0, stream>>>(w5, w5_bf, DOUT * H4dim / 4);

  // transposes (in [R][C] -> out [C][R]); grid = (C/32, R/32)
  transpose_cast_kernel<<<dim3(DIN / 32, H1dim / 32), 256, 0, stream>>>(w1, w1T, H1dim, DIN);
  transpose_cast_kernel<<<dim3(H3dim / 32, H4dim / 32), 256, 0, stream>>>(w4, w4T, H4dim, H3dim);
  transpose_cast_kernel<<<dim3(DOUT / 32, H3dim / 32), 256, 0, stream>>>(w3, w3T, H3dim, DOUT);

  // folded biases (ba independent; bc needs WtT)
  ba_kernel<<<DOUT / 4, 256, 0, stream>>>(b1, w2, b2, ba);

  // weight folds:
  // WaT[512][1024] = w2 @ w1  (A=w2_bf, Bt=w1T, K=4096)
  gemm_bt_kernel<MODE_BF16><<<dim3(DOUT / 128, DIN / 128), 256, 0, stream>>>(
      w2_bf, w1T, WaT, nullptr, nullptr, DOUT, DIN, H1dim);
  // WtT[512][2048] = w5 @ w4  (A=w5_bf, Bt=w4T, K=2048)
  gemm_bt_kernel<MODE_BF16><<<dim3(DOUT / 128, H3dim / 128), 256, 0, stream>>>(
      w5_bf, w4T, WtT, nullptr, nullptr, DOUT, H3dim, H4dim);
  bc_kernel<<<DOUT / 4, 256, 0, stream>>>(b3, WtT, b4, w5, b5, bc);
  // WcT[512][512] = WtT @ w3  (A=WtT, Bt=w3T, K=2048)
  gemm_bt_kernel<MODE_BF16><<<dim3(DOUT / 128, DOUT / 128), 256, 0, stream>>>(
      WtT, w3T, WcT, nullptr, nullptr, DOUT, DOUT, H3dim);

  // main: h2 = x@Wa + ba -> quantize -> q   (M=16384,N=512,K=1024)
  gemm_bt_kernel<MODE_Q><<<dim3(Bdim / 128, DOUT / 128), 256, 0, stream>>>(
      x_bf, WaT, q, ba, cb, Bdim, DOUT, DIN);
  // out = q@Wc + bc                          (M=16384,N=512,K=512)
  gemm_bt_kernel<MODE_OUT><<<dim3(Bdim / 128, DOUT / 128), 256, 0, stream>>>(
      q, WcT, out, bc, nullptr, Bdim, DOUT, DOUT);
}

// Round 2
// 330.284 us; speedup vs baseline: 1.3347x; 1.3347x over previous
//
#include <hip/hip_runtime.h>

// ---------------------------------------------------------------------------
// network_49581102465567: 5-layer linear MLP, codebook quantize after layer 2.
// Linear layers fold: Wa = w2@w1 [512x1024], Wc = (w5@w4)@w3 [512x512].
// Round 2: split-K fold GEMMs (64x64 tiles, fp32 partials + reduce) to fix
// the 1.4%-occupancy fold bottleneck (was 79us on 32 blocks).
// Main GEMMs (MODE_Q / MODE_OUT) numerically and structurally unchanged.
// ---------------------------------------------------------------------------

typedef __bf16 v8bf __attribute__((ext_vector_type(8)));
typedef float  v4f  __attribute__((ext_vector_type(4)));

#define Bdim   16384
#define DIN    1024
#define DOUT   512
#define H1dim  4096
#define H3dim  2048
#define H4dim  2048

// ---- elementwise cast fp32 -> bf16, 4 elems/thread ----
__global__ void cast_bf16_kernel(const float* __restrict__ in,
                                 __bf16* __restrict__ out, int n4) {
  int i = blockIdx.x * blockDim.x + threadIdx.x;
  if (i >= n4) return;
  float4 v = reinterpret_cast<const float4*>(in)[i];
  unsigned h0 = __builtin_bit_cast(unsigned short, (__bf16)v.x);
  unsigned h1 = __builtin_bit_cast(unsigned short, (__bf16)v.y);
  unsigned h2 = __builtin_bit_cast(unsigned short, (__bf16)v.z);
  unsigned h3 = __builtin_bit_cast(unsigned short, (__bf16)v.w);
  uint2 o;
  o.x = h0 | (h1 << 16);
  o.y = h2 | (h3 << 16);
  reinterpret_cast<uint2*>(out)[i] = o;
}

// ---- transpose + cast: in fp32 [R][C] -> out bf16 [C][R] ----
__global__ void transpose_cast_kernel(const float* __restrict__ in,
                                      __bf16* __restrict__ out, int R, int C) {
  __shared__ float tile[32][33];
  const int c0 = blockIdx.x * 32, r0 = blockIdx.y * 32;
  const int t = threadIdx.x, tr = t >> 5, tc = t & 31;
#pragma unroll
  for (int i = 0; i < 4; ++i)
    tile[tr + i * 8][tc] = in[(size_t)(r0 + tr + i * 8) * C + (c0 + tc)];
  __syncthreads();
#pragma unroll
  for (int i = 0; i < 4; ++i)
    out[(size_t)(c0 + tr + i * 8) * R + (r0 + tc)] = (__bf16)tile[tc][tr + i * 8];
}

// ---- folded bias vectors ----
__global__ void ba_kernel(const float* __restrict__ b1, const float* __restrict__ w2,
                          const float* __restrict__ b2, float* __restrict__ ba) {
  const int wave = threadIdx.x >> 6, lane = threadIdx.x & 63;
  const int j = blockIdx.x * 4 + wave;
  float s = 0.f;
  for (int k = lane; k < H1dim; k += 64) s += b1[k] * w2[(size_t)j * H1dim + k];
#pragma unroll
  for (int off = 32; off; off >>= 1) s += __shfl_xor(s, off, 64);
  if (lane == 0) ba[j] = s + b2[j];
}

__global__ void bc_kernel(const float* __restrict__ b3, const __bf16* __restrict__ WtT,
                          const float* __restrict__ b4, const float* __restrict__ w5,
                          const float* __restrict__ b5, float* __restrict__ bc) {
  const int wave = threadIdx.x >> 6, lane = threadIdx.x & 63;
  const int j = blockIdx.x * 4 + wave;
  float s = 0.f;
  for (int k = lane; k < H4dim; k += 64)
    s += b3[k] * (float)WtT[(size_t)j * H4dim + k] + b4[k] * w5[(size_t)j * H4dim + k];
#pragma unroll
  for (int off = 32; off; off >>= 1) s += __shfl_xor(s, off, 64);
  if (lane == 0) bc[j] = s + b5[j];
}

// ---- split-K fold GEMM: 64x64 tile, grid (M/64, N/64, S), Kchunk = K/S ----
// Cpart[s][m][n] = sum_{k in chunk s} A[m][k]*Bt[n][k]
__global__ __launch_bounds__(256, 4)
void gemm_bt_splitk_kernel(const __bf16* __restrict__ A, const __bf16* __restrict__ Bt,
                           float* __restrict__ Cpart, int M, int N, int K, int Kchunk) {
  __shared__ __bf16 As[64 * 32];
  __shared__ __bf16 Bs[64 * 32];
  const int t = threadIdx.x;
  const int m0 = blockIdx.x * 64;
  const int n0 = blockIdx.y * 64;
  const int kbeg = blockIdx.z * Kchunk;
  const int lane = t & 63, wave = t >> 6;
  const int quad = lane >> 4, l15 = lane & 15;
  const int wm = (wave & 1) * 32, wn = (wave >> 1) * 32;

  v4f acc[2][2];
#pragma unroll
  for (int i = 0; i < 2; ++i)
#pragma unroll
    for (int j = 0; j < 2; ++j) acc[i][j] = (v4f){0.f, 0.f, 0.f, 0.f};

  const int e = t * 8, r = e >> 5, c = e & 31;  // 64x32 tile: one pass/thread
  for (int k0 = kbeg; k0 < kbeg + Kchunk; k0 += 32) {
    *(int4*)&As[e] = *(const int4*)&A[(size_t)(m0 + r) * K + (k0 + c)];
    *(int4*)&Bs[e] = *(const int4*)&Bt[(size_t)(n0 + r) * K + (k0 + c)];
    __syncthreads();
    v8bf af[2], bfr[2];
#pragma unroll
    for (int i = 0; i < 2; ++i) {
      af[i]  = *(const v8bf*)&As[(wm + i * 16 + l15) * 32 + quad * 8];
      bfr[i] = *(const v8bf*)&Bs[(wn + i * 16 + l15) * 32 + quad * 8];
    }
#pragma unroll
    for (int i = 0; i < 2; ++i)
#pragma unroll
      for (int j = 0; j < 2; ++j)
        acc[i][j] = __builtin_amdgcn_mfma_f32_16x16x32_bf16(af[i], bfr[j], acc[i][j], 0, 0, 0);
    __syncthreads();
  }

  float* dst = Cpart + (size_t)blockIdx.z * M * N;
#pragma unroll
  for (int i = 0; i < 2; ++i)
#pragma unroll
    for (int j = 0; j < 2; ++j)
#pragma unroll
      for (int r2 = 0; r2 < 4; ++r2) {
        const int gm = m0 + wm + i * 16 + quad * 4 + r2;
        const int gn = n0 + wn + j * 16 + l15;
        dst[(size_t)gm * N + gn] = acc[i][j][r2];
      }
}

// ---- reduce S fp32 partial slices -> bf16 ----
__global__ void reduce_cast_kernel(const float* __restrict__ part,
                                   __bf16* __restrict__ out, int MN4, int S) {
  int i = blockIdx.x * blockDim.x + threadIdx.x;
  if (i >= MN4) return;
  const float4* p = reinterpret_cast<const float4*>(part);
  float4 s = p[i];
  for (int k = 1; k < S; ++k) {
    float4 v = p[(size_t)k * MN4 + i];
    s.x += v.x; s.y += v.y; s.z += v.z; s.w += v.w;
  }
  unsigned h0 = __builtin_bit_cast(unsigned short, (__bf16)s.x);
  unsigned h1 = __builtin_bit_cast(unsigned short, (__bf16)s.y);
  unsigned h2 = __builtin_bit_cast(unsigned short, (__bf16)s.z);
  unsigned h3 = __builtin_bit_cast(unsigned short, (__bf16)s.w);
  uint2 o;
  o.x = h0 | (h1 << 16);
  o.y = h2 | (h3 << 16);
  reinterpret_cast<uint2*>(out)[i] = o;
}

// ---- main B^T-form GEMM (unchanged from round 1) ----
enum { MODE_BF16 = 0, MODE_Q = 1, MODE_OUT = 2 };

template <int MODE>
__global__ __launch_bounds__(256, 2)
void gemm_bt_kernel(const __bf16* __restrict__ A, const __bf16* __restrict__ Bt,
                    void* __restrict__ Cout, const float* __restrict__ bias,
                    const float* __restrict__ codebook, int M, int N, int K) {
  __shared__ __bf16 As[128 * 32];
  __shared__ __bf16 Bs[128 * 32];
  __shared__ float cbs[256];

  const int t = threadIdx.x;
  const int m0 = blockIdx.x * 128;
  const int n0 = blockIdx.y * 128;
  if (MODE == MODE_Q) cbs[t] = codebook[t];

  const int lane = t & 63, wave = t >> 6;
  const int quad = lane >> 4, l15 = lane & 15;
  const int wm = (wave & 1) * 64, wn = (wave >> 1) * 64;

  v4f acc[4][4];
#pragma unroll
  for (int i = 0; i < 4; ++i)
#pragma unroll
    for (int j = 0; j < 4; ++j) acc[i][j] = (v4f){0.f, 0.f, 0.f, 0.f};

  for (int k0 = 0; k0 < K; k0 += 32) {
#pragma unroll
    for (int p = 0; p < 2; ++p) {
      const int e = (p * 256 + t) * 8;
      const int r = e >> 5, c = e & 31;
      *(int4*)&As[e] = *(const int4*)&A[(size_t)(m0 + r) * K + (k0 + c)];
      *(int4*)&Bs[e] = *(const int4*)&Bt[(size_t)(n0 + r) * K + (k0 + c)];
    }
    __syncthreads();

    v8bf af[4], bfr[4];
#pragma unroll
    for (int i = 0; i < 4; ++i) {
      af[i]  = *(const v8bf*)&As[(wm + i * 16 + l15) * 32 + quad * 8];
      bfr[i] = *(const v8bf*)&Bs[(wn + i * 16 + l15) * 32 + quad * 8];
    }
#pragma unroll
    for (int i = 0; i < 4; ++i)
#pragma unroll
      for (int j = 0; j < 4; ++j)
        acc[i][j] = __builtin_amdgcn_mfma_f32_16x16x32_bf16(af[i], bfr[j], acc[i][j], 0, 0, 0);
    __syncthreads();
  }

#pragma unroll
  for (int i = 0; i < 4; ++i) {
#pragma unroll
    for (int j = 0; j < 4; ++j) {
#pragma unroll
      for (int r = 0; r < 4; ++r) {
        const int gm = m0 + wm + i * 16 + quad * 4 + r;
        const int gn = n0 + wn + j * 16 + l15;
        float v = acc[i][j][r];
        if constexpr (MODE == MODE_BF16) {
          ((__bf16*)Cout)[(size_t)gm * N + gn] = (__bf16)v;
        } else if constexpr (MODE == MODE_Q) {
          v += bias[gn];
          int idx = 0;
#pragma unroll
          for (int s = 128; s > 0; s >>= 1) {
            const int u = idx + s;
            if (cbs[u] <= v) idx = u;
          }
          float best = cbs[idx];
          if (idx < 255) {
            const float c1 = cbs[idx + 1];
            if (!(v - best <= c1 - v)) best = c1;
          }
          ((__bf16*)Cout)[(size_t)gm * N + gn] = (__bf16)best;
        } else {
          v += bias[gn];
          ((float*)Cout)[(size_t)gm * N + gn] = v;
        }
      }
    }
  }
}

extern "C" void kernel_launch(void* const* d_in, const int* in_sizes, int n_in,
                              void* d_out, int out_size, void* d_ws, size_t ws_size,
                              hipStream_t stream) {
  const float* x  = (const float*)d_in[0];
  const float* cb = (const float*)d_in[1];
  const float* w1 = (const float*)d_in[2];   // [4096,1024]
  const float* b1 = (const float*)d_in[3];
  const float* w2 = (const float*)d_in[4];   // [512,4096]
  const float* b2 = (const float*)d_in[5];
  const float* w3 = (const float*)d_in[6];   // [2048,512]
  const float* b3 = (const float*)d_in[7];
  const float* w4 = (const float*)d_in[8];   // [2048,2048]
  const float* b4 = (const float*)d_in[9];
  const float* w5 = (const float*)d_in[10];  // [512,2048]
  const float* b5 = (const float*)d_in[11];
  float* out = (float*)d_out;

  char* ws = (char*)d_ws;
  size_t off = 0;
  auto alloc = [&](size_t bytes) -> void* {
    void* p = ws + off;
    off = (off + bytes + 255) & ~(size_t)255;
    return p;
  };
  __bf16* x_bf  = (__bf16*)alloc((size_t)Bdim * DIN * 2);
  __bf16* w1T   = (__bf16*)alloc((size_t)DIN * H1dim * 2);
  __bf16* w2_bf = (__bf16*)alloc((size_t)DOUT * H1dim * 2);
  __bf16* w4T   = (__bf16*)alloc((size_t)H3dim * H4dim * 2);
  __bf16* w3T   = (__bf16*)alloc((size_t)DOUT * H3dim * 2);
  __bf16* w5_bf = (__bf16*)alloc((size_t)DOUT * H4dim * 2);
  __bf16* WaT   = (__bf16*)alloc((size_t)DOUT * DIN * 2);
  __bf16* WtT   = (__bf16*)alloc((size_t)DOUT * H3dim * 2);
  __bf16* WcT   = (__bf16*)alloc((size_t)DOUT * DOUT * 2);
  __bf16* q     = (__bf16*)alloc((size_t)Bdim * DOUT * 2);
  float*  ba    = (float*)alloc(DOUT * 4);
  float*  bc    = (float*)alloc(DOUT * 4);
  // split-K partial scratch, reused by all three folds (max 8*512*1024*4 = 16.8 MB)
  float*  part  = (float*)alloc((size_t)8 * DOUT * DIN * 4 > (size_t)4 * DOUT * H3dim * 4
                                    ? (size_t)8 * DOUT * DIN * 4
                                    : (size_t)4 * DOUT * H3dim * 4);

  // casts
  cast_bf16_kernel<<<(Bdim * DIN / 4 + 255) / 256, 256, 0, stream>>>(x, x_bf, Bdim * DIN / 4);
  cast_bf16_kernel<<<(DOUT * H1dim / 4 + 255) / 256, 256, 0, stream>>>(w2, w2_bf, DOUT * H1dim / 4);
  cast_bf16_kernel<<<(DOUT * H4dim / 4 + 255) / 256, 256, 0, stream>>>(w5, w5_bf, DOUT * H4dim / 4);

  // transposes
  transpose_cast_kernel<<<dim3(DIN / 32, H1dim / 32), 256, 0, stream>>>(w1, w1T, H1dim, DIN);
  transpose_cast_kernel<<<dim3(H3dim / 32, H4dim / 32), 256, 0, stream>>>(w4, w4T, H4dim, H3dim);
  transpose_cast_kernel<<<dim3(DOUT / 32, H3dim / 32), 256, 0, stream>>>(w3, w3T, H3dim, DOUT);

  ba_kernel<<<DOUT / 4, 256, 0, stream>>>(b1, w2, b2, ba);

  // fold 1: WaT[512][1024] = w2 @ w1, K=4096, S=8 -> 8x16x8 = 1024 blocks
  gemm_bt_splitk_kernel<<<dim3(DOUT / 64, DIN / 64, 8), 256, 0, stream>>>(
      w2_bf, w1T, part, DOUT, DIN, H1dim, H1dim / 8);
  reduce_cast_kernel<<<(DOUT * DIN / 4 + 255) / 256, 256, 0, stream>>>(
      part, WaT, DOUT * DIN / 4, 8);

  // fold 2: WtT[512][2048] = w5 @ w4, K=2048, S=4 -> 8x32x4 = 1024 blocks
  gemm_bt_splitk_kernel<<<dim3(DOUT / 64, H3dim / 64, 4), 256, 0, stream>>>(
      w5_bf, w4T, part, DOUT, H3dim, H4dim, H4dim / 4);
  reduce_cast_kernel<<<(DOUT * H3dim / 4 + 255) / 256, 256, 0, stream>>>(
      part, WtT, DOUT * H3dim / 4, 4);

  bc_kernel<<<DOUT / 4, 256, 0, stream>>>(b3, WtT, b4, w5, b5, bc);

  // fold 3: WcT[512][512] = WtT @ w3, K=2048, S=8 -> 8x8x8 = 512 blocks
  gemm_bt_splitk_kernel<<<dim3(DOUT / 64, DOUT / 64, 8), 256, 0, stream>>>(
      WtT, w3T, part, DOUT, DOUT, H3dim, H3dim / 8);
  reduce_cast_kernel<<<(DOUT * DOUT / 4 + 255) / 256, 256, 0, stream>>>(
      part, WcT, DOUT * DOUT / 4, 8);

  // main: h2 = x@Wa + ba -> quantize -> q   (M=16384,N=512,K=1024)
  gemm_bt_kernel<MODE_Q><<<dim3(Bdim / 128, DOUT / 128), 256, 0, stream>>>(
      x_bf, WaT, q, ba, cb, Bdim, DOUT, DIN);
  // out = q@Wc + bc                          (M=16384,N=512,K=512)
  gemm_bt_kernel<MODE_OUT><<<dim3(Bdim / 128, DOUT / 128), 256, 0, stream>>>(
      q, WcT, out, bc, nullptr, Bdim, DOUT, DOUT);
}

// Round 3
// 330.229 us; speedup vs baseline: 1.3350x; 1.0002x over previous
//
#include <hip/hip_runtime.h>

// ---------------------------------------------------------------------------
// network_49581102465567: 5-layer linear MLP, codebook quantize after layer 2.
// Linear layers fold: Wa = w2@w1 [512x1024], Wc = (w5@w4)@w3 [512x512].
// Round 3: main GEMM staging via __builtin_amdgcn_global_load_lds width=16
// (m93->m97 ladder step, 517->874 TF). LDS layout unchanged (wave-uniform
// chunk base + lane*16B == row-major [128][32]), so numerics bit-identical.
// ---------------------------------------------------------------------------

typedef __bf16 v8bf __attribute__((ext_vector_type(8)));
typedef float  v4f  __attribute__((ext_vector_type(4)));

#define Bdim   16384
#define DIN    1024
#define DOUT   512
#define H1dim  4096
#define H3dim  2048
#define H4dim  2048

#define GLOBAL_AS __attribute__((address_space(1)))
#define LDS_AS    __attribute__((address_space(3)))

// direct global->LDS DMA, 16 B/lane; LDS dest is wave-uniform base + lane*16
__device__ __forceinline__ void load16_to_lds(const __bf16* g, __bf16* l) {
  __builtin_amdgcn_global_load_lds((const GLOBAL_AS unsigned int*)g,
                                   (LDS_AS unsigned int*)l, 16, 0, 0);
}

// ---- elementwise cast fp32 -> bf16, 4 elems/thread ----
__global__ void cast_bf16_kernel(const float* __restrict__ in,
                                 __bf16* __restrict__ out, int n4) {
  int i = blockIdx.x * blockDim.x + threadIdx.x;
  if (i >= n4) return;
  float4 v = reinterpret_cast<const float4*>(in)[i];
  unsigned h0 = __builtin_bit_cast(unsigned short, (__bf16)v.x);
  unsigned h1 = __builtin_bit_cast(unsigned short, (__bf16)v.y);
  unsigned h2 = __builtin_bit_cast(unsigned short, (__bf16)v.z);
  unsigned h3 = __builtin_bit_cast(unsigned short, (__bf16)v.w);
  uint2 o;
  o.x = h0 | (h1 << 16);
  o.y = h2 | (h3 << 16);
  reinterpret_cast<uint2*>(out)[i] = o;
}

// ---- transpose + cast: in fp32 [R][C] -> out bf16 [C][R] ----
__global__ void transpose_cast_kernel(const float* __restrict__ in,
                                      __bf16* __restrict__ out, int R, int C) {
  __shared__ float tile[32][33];
  const int c0 = blockIdx.x * 32, r0 = blockIdx.y * 32;
  const int t = threadIdx.x, tr = t >> 5, tc = t & 31;
#pragma unroll
  for (int i = 0; i < 4; ++i)
    tile[tr + i * 8][tc] = in[(size_t)(r0 + tr + i * 8) * C + (c0 + tc)];
  __syncthreads();
#pragma unroll
  for (int i = 0; i < 4; ++i)
    out[(size_t)(c0 + tr + i * 8) * R + (r0 + tc)] = (__bf16)tile[tc][tr + i * 8];
}

// ---- folded bias vectors ----
__global__ void ba_kernel(const float* __restrict__ b1, const float* __restrict__ w2,
                          const float* __restrict__ b2, float* __restrict__ ba) {
  const int wave = threadIdx.x >> 6, lane = threadIdx.x & 63;
  const int j = blockIdx.x * 4 + wave;
  float s = 0.f;
  for (int k = lane; k < H1dim; k += 64) s += b1[k] * w2[(size_t)j * H1dim + k];
#pragma unroll
  for (int off = 32; off; off >>= 1) s += __shfl_xor(s, off, 64);
  if (lane == 0) ba[j] = s + b2[j];
}

__global__ void bc_kernel(const float* __restrict__ b3, const __bf16* __restrict__ WtT,
                          const float* __restrict__ b4, const float* __restrict__ w5,
                          const float* __restrict__ b5, float* __restrict__ bc) {
  const int wave = threadIdx.x >> 6, lane = threadIdx.x & 63;
  const int j = blockIdx.x * 4 + wave;
  float s = 0.f;
  for (int k = lane; k < H4dim; k += 64)
    s += b3[k] * (float)WtT[(size_t)j * H4dim + k] + b4[k] * w5[(size_t)j * H4dim + k];
#pragma unroll
  for (int off = 32; off; off >>= 1) s += __shfl_xor(s, off, 64);
  if (lane == 0) bc[j] = s + b5[j];
}

// ---- split-K fold GEMM: 64x64 tile, grid (M/64, N/64, S), Kchunk = K/S ----
__global__ __launch_bounds__(256, 4)
void gemm_bt_splitk_kernel(const __bf16* __restrict__ A, const __bf16* __restrict__ Bt,
                           float* __restrict__ Cpart, int M, int N, int K, int Kchunk) {
  __shared__ __bf16 As[64 * 32];
  __shared__ __bf16 Bs[64 * 32];
  const int t = threadIdx.x;
  const int m0 = blockIdx.x * 64;
  const int n0 = blockIdx.y * 64;
  const int kbeg = blockIdx.z * Kchunk;
  const int lane = t & 63, wave = t >> 6;
  const int quad = lane >> 4, l15 = lane & 15;
  const int wm = (wave & 1) * 32, wn = (wave >> 1) * 32;

  v4f acc[2][2];
#pragma unroll
  for (int i = 0; i < 2; ++i)
#pragma unroll
    for (int j = 0; j < 2; ++j) acc[i][j] = (v4f){0.f, 0.f, 0.f, 0.f};

  const int e = t * 8, r = e >> 5, c = e & 31;
  for (int k0 = kbeg; k0 < kbeg + Kchunk; k0 += 32) {
    *(int4*)&As[e] = *(const int4*)&A[(size_t)(m0 + r) * K + (k0 + c)];
    *(int4*)&Bs[e] = *(const int4*)&Bt[(size_t)(n0 + r) * K + (k0 + c)];
    __syncthreads();
    v8bf af[2], bfr[2];
#pragma unroll
    for (int i = 0; i < 2; ++i) {
      af[i]  = *(const v8bf*)&As[(wm + i * 16 + l15) * 32 + quad * 8];
      bfr[i] = *(const v8bf*)&Bs[(wn + i * 16 + l15) * 32 + quad * 8];
    }
#pragma unroll
    for (int i = 0; i < 2; ++i)
#pragma unroll
      for (int j = 0; j < 2; ++j)
        acc[i][j] = __builtin_amdgcn_mfma_f32_16x16x32_bf16(af[i], bfr[j], acc[i][j], 0, 0, 0);
    __syncthreads();
  }

  float* dst = Cpart + (size_t)blockIdx.z * M * N;
#pragma unroll
  for (int i = 0; i < 2; ++i)
#pragma unroll
    for (int j = 0; j < 2; ++j)
#pragma unroll
      for (int r2 = 0; r2 < 4; ++r2) {
        const int gm = m0 + wm + i * 16 + quad * 4 + r2;
        const int gn = n0 + wn + j * 16 + l15;
        dst[(size_t)gm * N + gn] = acc[i][j][r2];
      }
}

// ---- reduce S fp32 partial slices -> bf16 ----
__global__ void reduce_cast_kernel(const float* __restrict__ part,
                                   __bf16* __restrict__ out, int MN4, int S) {
  int i = blockIdx.x * blockDim.x + threadIdx.x;
  if (i >= MN4) return;
  const float4* p = reinterpret_cast<const float4*>(part);
  float4 s = p[i];
  for (int k = 1; k < S; ++k) {
    float4 v = p[(size_t)k * MN4 + i];
    s.x += v.x; s.y += v.y; s.z += v.z; s.w += v.w;
  }
  unsigned h0 = __builtin_bit_cast(unsigned short, (__bf16)s.x);
  unsigned h1 = __builtin_bit_cast(unsigned short, (__bf16)s.y);
  unsigned h2 = __builtin_bit_cast(unsigned short, (__bf16)s.z);
  unsigned h3 = __builtin_bit_cast(unsigned short, (__bf16)s.w);
  uint2 o;
  o.x = h0 | (h1 << 16);
  o.y = h2 | (h3 << 16);
  reinterpret_cast<uint2*>(out)[i] = o;
}

// ---- main B^T-form GEMM with global_load_lds staging ----
enum { MODE_Q = 1, MODE_OUT = 2 };

template <int MODE>
__global__ __launch_bounds__(256, 2)
void gemm_bt_kernel(const __bf16* __restrict__ A, const __bf16* __restrict__ Bt,
                    void* __restrict__ Cout, const float* __restrict__ bias,
                    const float* __restrict__ codebook, int M, int N, int K) {
  __shared__ __bf16 As[128 * 32];
  __shared__ __bf16 Bs[128 * 32];
  __shared__ float cbs[256];

  const int t = threadIdx.x;
  const int m0 = blockIdx.x * 128;
  const int n0 = blockIdx.y * 128;
  if (MODE == MODE_Q) cbs[t] = codebook[t];

  const int lane = t & 63, wave = t >> 6;
  const int quad = lane >> 4, l15 = lane & 15;
  const int wm = (wave & 1) * 64, wn = (wave >> 1) * 64;

  // staging geometry: tile = 8 chunks of 1024B (16 rows x 64B); wave w does
  // chunks {w, w+4}; lane i covers row 16c + i/4, col (i%4)*8 (elements)
  const int srow0 = 16 * wave + (lane >> 2);
  const int srow1 = srow0 + 64;
  const int scol = (lane & 3) * 8;
  const __bf16* gA0 = A + (size_t)(m0 + srow0) * K + scol;
  const __bf16* gA1 = A + (size_t)(m0 + srow1) * K + scol;
  const __bf16* gB0 = Bt + (size_t)(n0 + srow0) * K + scol;
  const __bf16* gB1 = Bt + (size_t)(n0 + srow1) * K + scol;
  __bf16* lA0 = &As[wave * 512];
  __bf16* lA1 = &As[(wave + 4) * 512];
  __bf16* lB0 = &Bs[wave * 512];
  __bf16* lB1 = &Bs[(wave + 4) * 512];

  v4f acc[4][4];
#pragma unroll
  for (int i = 0; i < 4; ++i)
#pragma unroll
    for (int j = 0; j < 4; ++j) acc[i][j] = (v4f){0.f, 0.f, 0.f, 0.f};

  for (int k0 = 0; k0 < K; k0 += 32) {
    load16_to_lds(gA0 + k0, lA0);
    load16_to_lds(gA1 + k0, lA1);
    load16_to_lds(gB0 + k0, lB0);
    load16_to_lds(gB1 + k0, lB1);
    __syncthreads();

    v8bf af[4], bfr[4];
#pragma unroll
    for (int i = 0; i < 4; ++i) {
      af[i]  = *(const v8bf*)&As[(wm + i * 16 + l15) * 32 + quad * 8];
      bfr[i] = *(const v8bf*)&Bs[(wn + i * 16 + l15) * 32 + quad * 8];
    }
#pragma unroll
    for (int i = 0; i < 4; ++i)
#pragma unroll
      for (int j = 0; j < 4; ++j)
        acc[i][j] = __builtin_amdgcn_mfma_f32_16x16x32_bf16(af[i], bfr[j], acc[i][j], 0, 0, 0);
    __syncthreads();
  }

#pragma unroll
  for (int i = 0; i < 4; ++i) {
#pragma unroll
    for (int j = 0; j < 4; ++j) {
#pragma unroll
      for (int r = 0; r < 4; ++r) {
        const int gm = m0 + wm + i * 16 + quad * 4 + r;
        const int gn = n0 + wn + j * 16 + l15;
        float v = acc[i][j][r];
        if constexpr (MODE == MODE_Q) {
          v += bias[gn];
          int idx = 0;
#pragma unroll
          for (int s = 128; s > 0; s >>= 1) {
            const int u = idx + s;
            if (cbs[u] <= v) idx = u;
          }
          float best = cbs[idx];
          if (idx < 255) {
            const float c1 = cbs[idx + 1];
            if (!(v - best <= c1 - v)) best = c1;
          }
          ((__bf16*)Cout)[(size_t)gm * N + gn] = (__bf16)best;
        } else {
          v += bias[gn];
          ((float*)Cout)[(size_t)gm * N + gn] = v;
        }
      }
    }
  }
}

extern "C" void kernel_launch(void* const* d_in, const int* in_sizes, int n_in,
                              void* d_out, int out_size, void* d_ws, size_t ws_size,
                              hipStream_t stream) {
  const float* x  = (const float*)d_in[0];
  const float* cb = (const float*)d_in[1];
  const float* w1 = (const float*)d_in[2];   // [4096,1024]
  const float* b1 = (const float*)d_in[3];
  const float* w2 = (const float*)d_in[4];   // [512,4096]
  const float* b2 = (const float*)d_in[5];
  const float* w3 = (const float*)d_in[6];   // [2048,512]
  const float* b3 = (const float*)d_in[7];
  const float* w4 = (const float*)d_in[8];   // [2048,2048]
  const float* b4 = (const float*)d_in[9];
  const float* w5 = (const float*)d_in[10];  // [512,2048]
  const float* b5 = (const float*)d_in[11];
  float* out = (float*)d_out;

  char* ws = (char*)d_ws;
  size_t off = 0;
  auto alloc = [&](size_t bytes) -> void* {
    void* p = ws + off;
    off = (off + bytes + 255) & ~(size_t)255;
    return p;
  };
  __bf16* x_bf  = (__bf16*)alloc((size_t)Bdim * DIN * 2);
  __bf16* w1T   = (__bf16*)alloc((size_t)DIN * H1dim * 2);
  __bf16* w2_bf = (__bf16*)alloc((size_t)DOUT * H1dim * 2);
  __bf16* w4T   = (__bf16*)alloc((size_t)H3dim * H4dim * 2);
  __bf16* w3T   = (__bf16*)alloc((size_t)DOUT * H3dim * 2);
  __bf16* w5_bf = (__bf16*)alloc((size_t)DOUT * H4dim * 2);
  __bf16* WaT   = (__bf16*)alloc((size_t)DOUT * DIN * 2);
  __bf16* WtT   = (__bf16*)alloc((size_t)DOUT * H3dim * 2);
  __bf16* WcT   = (__bf16*)alloc((size_t)DOUT * DOUT * 2);
  __bf16* q     = (__bf16*)alloc((size_t)Bdim * DOUT * 2);
  float*  ba    = (float*)alloc(DOUT * 4);
  float*  bc    = (float*)alloc(DOUT * 4);
  float*  part  = (float*)alloc((size_t)8 * DOUT * DIN * 4);

  // casts
  cast_bf16_kernel<<<(Bdim * DIN / 4 + 255) / 256, 256, 0, stream>>>(x, x_bf, Bdim * DIN / 4);
  cast_bf16_kernel<<<(DOUT * H1dim / 4 + 255) / 256, 256, 0, stream>>>(w2, w2_bf, DOUT * H1dim / 4);
  cast_bf16_kernel<<<(DOUT * H4dim / 4 + 255) / 256, 256, 0, stream>>>(w5, w5_bf, DOUT * H4dim / 4);

  // transposes
  transpose_cast_kernel<<<dim3(DIN / 32, H1dim / 32), 256, 0, stream>>>(w1, w1T, H1dim, DIN);
  transpose_cast_kernel<<<dim3(H3dim / 32, H4dim / 32), 256, 0, stream>>>(w4, w4T, H4dim, H3dim);
  transpose_cast_kernel<<<dim3(DOUT / 32, H3dim / 32), 256, 0, stream>>>(w3, w3T, H3dim, DOUT);

  ba_kernel<<<DOUT / 4, 256, 0, stream>>>(b1, w2, b2, ba);

  // fold 1: WaT = w2 @ w1, K=4096, S=8
  gemm_bt_splitk_kernel<<<dim3(DOUT / 64, DIN / 64, 8), 256, 0, stream>>>(
      w2_bf, w1T, part, DOUT, DIN, H1dim, H1dim / 8);
  reduce_cast_kernel<<<(DOUT * DIN / 4 + 255) / 256, 256, 0, stream>>>(
      part, WaT, DOUT * DIN / 4, 8);

  // fold 2: WtT = w5 @ w4, K=2048, S=4
  gemm_bt_splitk_kernel<<<dim3(DOUT / 64, H3dim / 64, 4), 256, 0, stream>>>(
      w5_bf, w4T, part, DOUT, H3dim, H4dim, H4dim / 4);
  reduce_cast_kernel<<<(DOUT * H3dim / 4 + 255) / 256, 256, 0, stream>>>(
      part, WtT, DOUT * H3dim / 4, 4);

  bc_kernel<<<DOUT / 4, 256, 0, stream>>>(b3, WtT, b4, w5, b5, bc);

  // fold 3: WcT = WtT @ w3, K=2048, S=8
  gemm_bt_splitk_kernel<<<dim3(DOUT / 64, DOUT / 64, 8), 256, 0, stream>>>(
      WtT, w3T, part, DOUT, DOUT, H3dim, H3dim / 8);
  reduce_cast_kernel<<<(DOUT * DOUT / 4 + 255) / 256, 256, 0, stream>>>(
      part, WcT, DOUT * DOUT / 4, 8);

  // main: h2 = x@Wa + ba -> quantize -> q   (M=16384,N=512,K=1024)
  gemm_bt_kernel<MODE_Q><<<dim3(Bdim / 128, DOUT / 128), 256, 0, stream>>>(
      x_bf, WaT, q, ba, cb, Bdim, DOUT, DIN);
  // out = q@Wc + bc                          (M=16384,N=512,K=512)
  gemm_bt_kernel<MODE_OUT><<<dim3(Bdim / 128, DOUT / 128), 256, 0, stream>>>(
      q, WcT, out, bc, nullptr, Bdim, DOUT, DOUT);
}

// Round 4
// 321.637 us; speedup vs baseline: 1.3706x; 1.0267x over previous
//
#include <hip/hip_runtime.h>

// ---------------------------------------------------------------------------
// network_49581102465567: 5-layer linear MLP, codebook quantize after layer 2.
// Linear layers fold: Wa = w2@w1 [512x1024], Wc = (w5@w4)@w3 [512x512].
// Round 4: main GEMM tile 128x128 -> 128x64. R3 showed the bottleneck is
// occupancy (19.6%, 2 blocks/CU at grid 512), not staging: barrier drains
// can't be hidden with 2 waves/SIMD. Grid -> 1024 blocks = 4 blocks/CU.
// ---------------------------------------------------------------------------

typedef __bf16 v8bf __attribute__((ext_vector_type(8)));
typedef float  v4f  __attribute__((ext_vector_type(4)));

#define Bdim   16384
#define DIN    1024
#define DOUT   512
#define H1dim  4096
#define H3dim  2048
#define H4dim  2048

#define GLOBAL_AS __attribute__((address_space(1)))
#define LDS_AS    __attribute__((address_space(3)))

__device__ __forceinline__ void load16_to_lds(const __bf16* g, __bf16* l) {
  __builtin_amdgcn_global_load_lds((const GLOBAL_AS unsigned int*)g,
                                   (LDS_AS unsigned int*)l, 16, 0, 0);
}

// ---- elementwise cast fp32 -> bf16, 4 elems/thread ----
__global__ void cast_bf16_kernel(const float* __restrict__ in,
                                 __bf16* __restrict__ out, int n4) {
  int i = blockIdx.x * blockDim.x + threadIdx.x;
  if (i >= n4) return;
  float4 v = reinterpret_cast<const float4*>(in)[i];
  unsigned h0 = __builtin_bit_cast(unsigned short, (__bf16)v.x);
  unsigned h1 = __builtin_bit_cast(unsigned short, (__bf16)v.y);
  unsigned h2 = __builtin_bit_cast(unsigned short, (__bf16)v.z);
  unsigned h3 = __builtin_bit_cast(unsigned short, (__bf16)v.w);
  uint2 o;
  o.x = h0 | (h1 << 16);
  o.y = h2 | (h3 << 16);
  reinterpret_cast<uint2*>(out)[i] = o;
}

// ---- transpose + cast: in fp32 [R][C] -> out bf16 [C][R] ----
__global__ void transpose_cast_kernel(const float* __restrict__ in,
                                      __bf16* __restrict__ out, int R, int C) {
  __shared__ float tile[32][33];
  const int c0 = blockIdx.x * 32, r0 = blockIdx.y * 32;
  const int t = threadIdx.x, tr = t >> 5, tc = t & 31;
#pragma unroll
  for (int i = 0; i < 4; ++i)
    tile[tr + i * 8][tc] = in[(size_t)(r0 + tr + i * 8) * C + (c0 + tc)];
  __syncthreads();
#pragma unroll
  for (int i = 0; i < 4; ++i)
    out[(size_t)(c0 + tr + i * 8) * R + (r0 + tc)] = (__bf16)tile[tc][tr + i * 8];
}

// ---- folded bias vectors ----
__global__ void ba_kernel(const float* __restrict__ b1, const float* __restrict__ w2,
                          const float* __restrict__ b2, float* __restrict__ ba) {
  const int wave = threadIdx.x >> 6, lane = threadIdx.x & 63;
  const int j = blockIdx.x * 4 + wave;
  float s = 0.f;
  for (int k = lane; k < H1dim; k += 64) s += b1[k] * w2[(size_t)j * H1dim + k];
#pragma unroll
  for (int off = 32; off; off >>= 1) s += __shfl_xor(s, off, 64);
  if (lane == 0) ba[j] = s + b2[j];
}

__global__ void bc_kernel(const float* __restrict__ b3, const __bf16* __restrict__ WtT,
                          const float* __restrict__ b4, const float* __restrict__ w5,
                          const float* __restrict__ b5, float* __restrict__ bc) {
  const int wave = threadIdx.x >> 6, lane = threadIdx.x & 63;
  const int j = blockIdx.x * 4 + wave;
  float s = 0.f;
  for (int k = lane; k < H4dim; k += 64)
    s += b3[k] * (float)WtT[(size_t)j * H4dim + k] + b4[k] * w5[(size_t)j * H4dim + k];
#pragma unroll
  for (int off = 32; off; off >>= 1) s += __shfl_xor(s, off, 64);
  if (lane == 0) bc[j] = s + b5[j];
}

// ---- split-K fold GEMM: 64x64 tile, grid (M/64, N/64, S), Kchunk = K/S ----
__global__ __launch_bounds__(256, 4)
void gemm_bt_splitk_kernel(const __bf16* __restrict__ A, const __bf16* __restrict__ Bt,
                           float* __restrict__ Cpart, int M, int N, int K, int Kchunk) {
  __shared__ __bf16 As[64 * 32];
  __shared__ __bf16 Bs[64 * 32];
  const int t = threadIdx.x;
  const int m0 = blockIdx.x * 64;
  const int n0 = blockIdx.y * 64;
  const int kbeg = blockIdx.z * Kchunk;
  const int lane = t & 63, wave = t >> 6;
  const int quad = lane >> 4, l15 = lane & 15;
  const int wm = (wave & 1) * 32, wn = (wave >> 1) * 32;

  v4f acc[2][2];
#pragma unroll
  for (int i = 0; i < 2; ++i)
#pragma unroll
    for (int j = 0; j < 2; ++j) acc[i][j] = (v4f){0.f, 0.f, 0.f, 0.f};

  const int e = t * 8, r = e >> 5, c = e & 31;
  for (int k0 = kbeg; k0 < kbeg + Kchunk; k0 += 32) {
    *(int4*)&As[e] = *(const int4*)&A[(size_t)(m0 + r) * K + (k0 + c)];
    *(int4*)&Bs[e] = *(const int4*)&Bt[(size_t)(n0 + r) * K + (k0 + c)];
    __syncthreads();
    v8bf af[2], bfr[2];
#pragma unroll
    for (int i = 0; i < 2; ++i) {
      af[i]  = *(const v8bf*)&As[(wm + i * 16 + l15) * 32 + quad * 8];
      bfr[i] = *(const v8bf*)&Bs[(wn + i * 16 + l15) * 32 + quad * 8];
    }
#pragma unroll
    for (int i = 0; i < 2; ++i)
#pragma unroll
      for (int j = 0; j < 2; ++j)
        acc[i][j] = __builtin_amdgcn_mfma_f32_16x16x32_bf16(af[i], bfr[j], acc[i][j], 0, 0, 0);
    __syncthreads();
  }

  float* dst = Cpart + (size_t)blockIdx.z * M * N;
#pragma unroll
  for (int i = 0; i < 2; ++i)
#pragma unroll
    for (int j = 0; j < 2; ++j)
#pragma unroll
      for (int r2 = 0; r2 < 4; ++r2) {
        const int gm = m0 + wm + i * 16 + quad * 4 + r2;
        const int gn = n0 + wn + j * 16 + l15;
        dst[(size_t)gm * N + gn] = acc[i][j][r2];
      }
}

// ---- reduce S fp32 partial slices -> bf16 ----
__global__ void reduce_cast_kernel(const float* __restrict__ part,
                                   __bf16* __restrict__ out, int MN4, int S) {
  int i = blockIdx.x * blockDim.x + threadIdx.x;
  if (i >= MN4) return;
  const float4* p = reinterpret_cast<const float4*>(part);
  float4 s = p[i];
  for (int k = 1; k < S; ++k) {
    float4 v = p[(size_t)k * MN4 + i];
    s.x += v.x; s.y += v.y; s.z += v.z; s.w += v.w;
  }
  unsigned h0 = __builtin_bit_cast(unsigned short, (__bf16)s.x);
  unsigned h1 = __builtin_bit_cast(unsigned short, (__bf16)s.y);
  unsigned h2 = __builtin_bit_cast(unsigned short, (__bf16)s.z);
  unsigned h3 = __builtin_bit_cast(unsigned short, (__bf16)s.w);
  uint2 o;
  o.x = h0 | (h1 << 16);
  o.y = h2 | (h3 << 16);
  reinterpret_cast<uint2*>(out)[i] = o;
}

// ---- main B^T-form GEMM: 128x64 tile, 4 waves in 2x2 (64m x 32n each) ----
enum { MODE_Q = 1, MODE_OUT = 2 };

template <int MODE>
__global__ __launch_bounds__(256, 4)
void gemm_bt_kernel(const __bf16* __restrict__ A, const __bf16* __restrict__ Bt,
                    void* __restrict__ Cout, const float* __restrict__ bias,
                    const float* __restrict__ codebook, int M, int N, int K) {
  __shared__ __bf16 As[128 * 32];   // 8 KB
  __shared__ __bf16 Bs[64 * 32];    // 4 KB
  __shared__ float cbs[256];

  const int t = threadIdx.x;
  const int m0 = blockIdx.x * 128;
  const int n0 = blockIdx.y * 64;
  if (MODE == MODE_Q) cbs[t] = codebook[t];

  const int lane = t & 63, wave = t >> 6;
  const int quad = lane >> 4, l15 = lane & 15;
  const int wm = (wave & 1) * 64, wn = (wave >> 1) * 32;

  // staging: A tile = 8 chunks of 1024B (16 rows x 64B), wave w -> {w, w+4};
  // B tile = 4 chunks, wave w -> {w}. lane i: row 16c + i/4, col (i%4)*8 elems
  const int srow = (lane >> 2);
  const int scol = (lane & 3) * 8;
  const __bf16* gA0 = A + (size_t)(m0 + 16 * wave + srow) * K + scol;
  const __bf16* gA1 = A + (size_t)(m0 + 64 + 16 * wave + srow) * K + scol;
  const __bf16* gB0 = Bt + (size_t)(n0 + 16 * wave + srow) * K + scol;
  __bf16* lA0 = &As[wave * 512];
  __bf16* lA1 = &As[(wave + 4) * 512];
  __bf16* lB0 = &Bs[wave * 512];

  v4f acc[4][2];
#pragma unroll
  for (int i = 0; i < 4; ++i)
#pragma unroll
    for (int j = 0; j < 2; ++j) acc[i][j] = (v4f){0.f, 0.f, 0.f, 0.f};

  for (int k0 = 0; k0 < K; k0 += 32) {
    load16_to_lds(gA0 + k0, lA0);
    load16_to_lds(gA1 + k0, lA1);
    load16_to_lds(gB0 + k0, lB0);
    __syncthreads();

    v8bf af[4], bfr[2];
#pragma unroll
    for (int i = 0; i < 4; ++i)
      af[i] = *(const v8bf*)&As[(wm + i * 16 + l15) * 32 + quad * 8];
#pragma unroll
    for (int j = 0; j < 2; ++j)
      bfr[j] = *(const v8bf*)&Bs[(wn + j * 16 + l15) * 32 + quad * 8];
#pragma unroll
    for (int i = 0; i < 4; ++i)
#pragma unroll
      for (int j = 0; j < 2; ++j)
        acc[i][j] = __builtin_amdgcn_mfma_f32_16x16x32_bf16(af[i], bfr[j], acc[i][j], 0, 0, 0);
    __syncthreads();
  }

#pragma unroll
  for (int i = 0; i < 4; ++i) {
#pragma unroll
    for (int j = 0; j < 2; ++j) {
#pragma unroll
      for (int r = 0; r < 4; ++r) {
        const int gm = m0 + wm + i * 16 + quad * 4 + r;
        const int gn = n0 + wn + j * 16 + l15;
        float v = acc[i][j][r];
        if constexpr (MODE == MODE_Q) {
          v += bias[gn];
          int idx = 0;
#pragma unroll
          for (int s = 128; s > 0; s >>= 1) {
            const int u = idx + s;
            if (cbs[u] <= v) idx = u;
          }
          float best = cbs[idx];
          if (idx < 255) {
            const float c1 = cbs[idx + 1];
            if (!(v - best <= c1 - v)) best = c1;
          }
          ((__bf16*)Cout)[(size_t)gm * N + gn] = (__bf16)best;
        } else {
          v += bias[gn];
          ((float*)Cout)[(size_t)gm * N + gn] = v;
        }
      }
    }
  }
}

extern "C" void kernel_launch(void* const* d_in, const int* in_sizes, int n_in,
                              void* d_out, int out_size, void* d_ws, size_t ws_size,
                              hipStream_t stream) {
  const float* x  = (const float*)d_in[0];
  const float* cb = (const float*)d_in[1];
  const float* w1 = (const float*)d_in[2];   // [4096,1024]
  const float* b1 = (const float*)d_in[3];
  const float* w2 = (const float*)d_in[4];   // [512,4096]
  const float* b2 = (const float*)d_in[5];
  const float* w3 = (const float*)d_in[6];   // [2048,512]
  const float* b3 = (const float*)d_in[7];
  const float* w4 = (const float*)d_in[8];   // [2048,2048]
  const float* b4 = (const float*)d_in[9];
  const float* w5 = (const float*)d_in[10];  // [512,2048]
  const float* b5 = (const float*)d_in[11];
  float* out = (float*)d_out;

  char* ws = (char*)d_ws;
  size_t off = 0;
  auto alloc = [&](size_t bytes) -> void* {
    void* p = ws + off;
    off = (off + bytes + 255) & ~(size_t)255;
    return p;
  };
  __bf16* x_bf  = (__bf16*)alloc((size_t)Bdim * DIN * 2);
  __bf16* w1T   = (__bf16*)alloc((size_t)DIN * H1dim * 2);
  __bf16* w2_bf = (__bf16*)alloc((size_t)DOUT * H1dim * 2);
  __bf16* w4T   = (__bf16*)alloc((size_t)H3dim * H4dim * 2);
  __bf16* w3T   = (__bf16*)alloc((size_t)DOUT * H3dim * 2);
  __bf16* w5_bf = (__bf16*)alloc((size_t)DOUT * H4dim * 2);
  __bf16* WaT   = (__bf16*)alloc((size_t)DOUT * DIN * 2);
  __bf16* WtT   = (__bf16*)alloc((size_t)DOUT * H3dim * 2);
  __bf16* WcT   = (__bf16*)alloc((size_t)DOUT * DOUT * 2);
  __bf16* q     = (__bf16*)alloc((size_t)Bdim * DOUT * 2);
  float*  ba    = (float*)alloc(DOUT * 4);
  float*  bc    = (float*)alloc(DOUT * 4);
  float*  part  = (float*)alloc((size_t)8 * DOUT * DIN * 4);

  // casts
  cast_bf16_kernel<<<(Bdim * DIN / 4 + 255) / 256, 256, 0, stream>>>(x, x_bf, Bdim * DIN / 4);
  cast_bf16_kernel<<<(DOUT * H1dim / 4 + 255) / 256, 256, 0, stream>>>(w2, w2_bf, DOUT * H1dim / 4);
  cast_bf16_kernel<<<(DOUT * H4dim / 4 + 255) / 256, 256, 0, stream>>>(w5, w5_bf, DOUT * H4dim / 4);

  // transposes
  transpose_cast_kernel<<<dim3(DIN / 32, H1dim / 32), 256, 0, stream>>>(w1, w1T, H1dim, DIN);
  transpose_cast_kernel<<<dim3(H3dim / 32, H4dim / 32), 256, 0, stream>>>(w4, w4T, H4dim, H3dim);
  transpose_cast_kernel<<<dim3(DOUT / 32, H3dim / 32), 256, 0, stream>>>(w3, w3T, H3dim, DOUT);

  ba_kernel<<<DOUT / 4, 256, 0, stream>>>(b1, w2, b2, ba);

  // fold 1: WaT = w2 @ w1, K=4096, S=8
  gemm_bt_splitk_kernel<<<dim3(DOUT / 64, DIN / 64, 8), 256, 0, stream>>>(
      w2_bf, w1T, part, DOUT, DIN, H1dim, H1dim / 8);
  reduce_cast_kernel<<<(DOUT * DIN / 4 + 255) / 256, 256, 0, stream>>>(
      part, WaT, DOUT * DIN / 4, 8);

  // fold 2: WtT = w5 @ w4, K=2048, S=4
  gemm_bt_splitk_kernel<<<dim3(DOUT / 64, H3dim / 64, 4), 256, 0, stream>>>(
      w5_bf, w4T, part, DOUT, H3dim, H4dim, H4dim / 4);
  reduce_cast_kernel<<<(DOUT * H3dim / 4 + 255) / 256, 256, 0, stream>>>(
      part, WtT, DOUT * H3dim / 4, 4);

  bc_kernel<<<DOUT / 4, 256, 0, stream>>>(b3, WtT, b4, w5, b5, bc);

  // fold 3: WcT = WtT @ w3, K=2048, S=8
  gemm_bt_splitk_kernel<<<dim3(DOUT / 64, DOUT / 64, 8), 256, 0, stream>>>(
      WtT, w3T, part, DOUT, DOUT, H3dim, H3dim / 8);
  reduce_cast_kernel<<<(DOUT * DOUT / 4 + 255) / 256, 256, 0, stream>>>(
      part, WcT, DOUT * DOUT / 4, 8);

  // main: h2 = x@Wa + ba -> quantize -> q   (M=16384,N=512,K=1024), 1024 blocks
  gemm_bt_kernel<MODE_Q><<<dim3(Bdim / 128, DOUT / 64), 256, 0, stream>>>(
      x_bf, WaT, q, ba, cb, Bdim, DOUT, DIN);
  // out = q@Wc + bc                          (M=16384,N=512,K=512), 1024 blocks
  gemm_bt_kernel<MODE_OUT><<<dim3(Bdim / 128, DOUT / 64), 256, 0, stream>>>(
      q, WcT, out, bc, nullptr, Bdim, DOUT, DOUT);
}

// Round 5
// 305.885 us; speedup vs baseline: 1.4412x; 1.0515x over previous
//
#include <hip/hip_runtime.h>

// ---------------------------------------------------------------------------
// network_49581102465567: 5-layer linear MLP, codebook quantize after layer 2.
// Linear layers fold: Wa = w2@w1 [512x1024], Wc = (w5@w4)@w3 [512x512].
// Round 5: overhead attack. Main GEMMs are only ~80us of 321; the rest is
// preprocessing. Fuse fp32->bf16 casts into consumers (kill 3 cast kernels,
// incl. the 100MB x-cast), merge ba+bc into one dispatch. 16 -> 12 kernels.
// All numeric paths bit-identical to R4 (same RNE casts, same sum orders).
// ---------------------------------------------------------------------------

typedef __bf16 v8bf __attribute__((ext_vector_type(8)));
typedef float  v4f  __attribute__((ext_vector_type(4)));

#define Bdim   16384
#define DIN    1024
#define DOUT   512
#define H1dim  4096
#define H3dim  2048
#define H4dim  2048

#define GLOBAL_AS __attribute__((address_space(1)))
#define LDS_AS    __attribute__((address_space(3)))

__device__ __forceinline__ void load16_to_lds(const __bf16* g, __bf16* l) {
  __builtin_amdgcn_global_load_lds((const GLOBAL_AS unsigned int*)g,
                                   (LDS_AS unsigned int*)l, 16, 0, 0);
}

__device__ __forceinline__ unsigned pack2bf(float a, float b) {
  return (unsigned)__builtin_bit_cast(unsigned short, (__bf16)a) |
         ((unsigned)__builtin_bit_cast(unsigned short, (__bf16)b) << 16);
}

// ---- transpose + cast: in fp32 [R][C] -> out bf16 [C][R] ----
__global__ void transpose_cast_kernel(const float* __restrict__ in,
                                      __bf16* __restrict__ out, int R, int C) {
  __shared__ float tile[32][33];
  const int c0 = blockIdx.x * 32, r0 = blockIdx.y * 32;
  const int t = threadIdx.x, tr = t >> 5, tc = t & 31;
#pragma unroll
  for (int i = 0; i < 4; ++i)
    tile[tr + i * 8][tc] = in[(size_t)(r0 + tr + i * 8) * C + (c0 + tc)];
  __syncthreads();
#pragma unroll
  for (int i = 0; i < 4; ++i)
    out[(size_t)(c0 + tr + i * 8) * R + (r0 + tc)] = (__bf16)tile[tc][tr + i * 8];
}

// ---- folded bias vectors: ba (blocks 0..127) and bc (blocks 128..255) ----
// Per-wave work identical to R4's ba_kernel/bc_kernel -> bit-identical sums.
__global__ void bias_kernel(const float* __restrict__ b1, const float* __restrict__ w2,
                            const float* __restrict__ b2, const float* __restrict__ b3,
                            const __bf16* __restrict__ WtT, const float* __restrict__ b4,
                            const float* __restrict__ w5, const float* __restrict__ b5,
                            float* __restrict__ ba, float* __restrict__ bc) {
  const int wave = threadIdx.x >> 6, lane = threadIdx.x & 63;
  if (blockIdx.x < 128) {
    const int j = blockIdx.x * 4 + wave;
    float s = 0.f;
    for (int k = lane; k < H1dim; k += 64) s += b1[k] * w2[(size_t)j * H1dim + k];
#pragma unroll
    for (int off = 32; off; off >>= 1) s += __shfl_xor(s, off, 64);
    if (lane == 0) ba[j] = s + b2[j];
  } else {
    const int j = (blockIdx.x - 128) * 4 + wave;
    float s = 0.f;
    for (int k = lane; k < H4dim; k += 64)
      s += b3[k] * (float)WtT[(size_t)j * H4dim + k] + b4[k] * w5[(size_t)j * H4dim + k];
#pragma unroll
    for (int off = 32; off; off >>= 1) s += __shfl_xor(s, off, 64);
    if (lane == 0) bc[j] = s + b5[j];
  }
}

// ---- split-K fold GEMM: 64x64 tile, grid (M/64, N/64, S), Kchunk = K/S ----
// A operand fp32 (cast in staging, RNE -> same bf16 values as R4) or bf16.
template <bool ABF16>
__global__ __launch_bounds__(256, 4)
void gemm_bt_splitk_kernel(const void* __restrict__ Ain, const __bf16* __restrict__ Bt,
                           float* __restrict__ Cpart, int M, int N, int K, int Kchunk) {
  __shared__ __bf16 As[64 * 32];
  __shared__ __bf16 Bs[64 * 32];
  const int t = threadIdx.x;
  const int m0 = blockIdx.x * 64;
  const int n0 = blockIdx.y * 64;
  const int kbeg = blockIdx.z * Kchunk;
  const int lane = t & 63, wave = t >> 6;
  const int quad = lane >> 4, l15 = lane & 15;
  const int wm = (wave & 1) * 32, wn = (wave >> 1) * 32;

  v4f acc[2][2];
#pragma unroll
  for (int i = 0; i < 2; ++i)
#pragma unroll
    for (int j = 0; j < 2; ++j) acc[i][j] = (v4f){0.f, 0.f, 0.f, 0.f};

  const int e = t * 8, r = e >> 5, c = e & 31;
  for (int k0 = kbeg; k0 < kbeg + Kchunk; k0 += 32) {
    if constexpr (ABF16) {
      const __bf16* A = (const __bf16*)Ain;
      *(int4*)&As[e] = *(const int4*)&A[(size_t)(m0 + r) * K + (k0 + c)];
    } else {
      const float* A = (const float*)Ain;
#pragma unroll
      for (int p = 0; p < 2; ++p) {
        const int idx = p * 256 + t;          // float4 index over 64x32 tile
        const int row = idx >> 3, col = (idx & 7) * 4;
        float4 v = *(const float4*)&A[(size_t)(m0 + row) * K + (k0 + col)];
        uint2 o;
        o.x = pack2bf(v.x, v.y);
        o.y = pack2bf(v.z, v.w);
        *(uint2*)&As[row * 32 + col] = o;
      }
    }
    *(int4*)&Bs[e] = *(const int4*)&Bt[(size_t)(n0 + r) * K + (k0 + c)];
    __syncthreads();
    v8bf af[2], bfr[2];
#pragma unroll
    for (int i = 0; i < 2; ++i) {
      af[i]  = *(const v8bf*)&As[(wm + i * 16 + l15) * 32 + quad * 8];
      bfr[i] = *(const v8bf*)&Bs[(wn + i * 16 + l15) * 32 + quad * 8];
    }
#pragma unroll
    for (int i = 0; i < 2; ++i)
#pragma unroll
      for (int j = 0; j < 2; ++j)
        acc[i][j] = __builtin_amdgcn_mfma_f32_16x16x32_bf16(af[i], bfr[j], acc[i][j], 0, 0, 0);
    __syncthreads();
  }

  float* dst = Cpart + (size_t)blockIdx.z * M * N;
#pragma unroll
  for (int i = 0; i < 2; ++i)
#pragma unroll
    for (int j = 0; j < 2; ++j)
#pragma unroll
      for (int r2 = 0; r2 < 4; ++r2) {
        const int gm = m0 + wm + i * 16 + quad * 4 + r2;
        const int gn = n0 + wn + j * 16 + l15;
        dst[(size_t)gm * N + gn] = acc[i][j][r2];
      }
}

// ---- reduce S fp32 partial slices -> bf16 ----
__global__ void reduce_cast_kernel(const float* __restrict__ part,
                                   __bf16* __restrict__ out, int MN4, int S) {
  int i = blockIdx.x * blockDim.x + threadIdx.x;
  if (i >= MN4) return;
  const float4* p = reinterpret_cast<const float4*>(part);
  float4 s = p[i];
  for (int k = 1; k < S; ++k) {
    float4 v = p[(size_t)k * MN4 + i];
    s.x += v.x; s.y += v.y; s.z += v.z; s.w += v.w;
  }
  uint2 o;
  o.x = pack2bf(s.x, s.y);
  o.y = pack2bf(s.z, s.w);
  reinterpret_cast<uint2*>(out)[i] = o;
}

// ---- main B^T-form GEMM: 128x64 tile, 4 waves in 2x2 (64m x 32n each) ----
// MODE_Q: A is fp32 (x), cast during staging. MODE_OUT: A is bf16 (q), DMA.
enum { MODE_Q = 1, MODE_OUT = 2 };

template <int MODE>
__global__ __launch_bounds__(256, 4)
void gemm_bt_kernel(const void* __restrict__ Ain, const __bf16* __restrict__ Bt,
                    void* __restrict__ Cout, const float* __restrict__ bias,
                    const float* __restrict__ codebook, int M, int N, int K) {
  __shared__ __bf16 As[128 * 32];   // 8 KB
  __shared__ __bf16 Bs[64 * 32];    // 4 KB
  __shared__ float cbs[256];

  const int t = threadIdx.x;
  const int m0 = blockIdx.x * 128;
  const int n0 = blockIdx.y * 64;
  if (MODE == MODE_Q) cbs[t] = codebook[t];

  const int lane = t & 63, wave = t >> 6;
  const int quad = lane >> 4, l15 = lane & 15;
  const int wm = (wave & 1) * 64, wn = (wave >> 1) * 32;

  // B staging via DMA: tile 64x32 = 4 chunks of 1024B (16 rows x 64B)
  const int srow = (lane >> 2);
  const int scol = (lane & 3) * 8;
  const __bf16* gB0 = Bt + (size_t)(n0 + 16 * wave + srow) * K + scol;
  __bf16* lB0 = &Bs[wave * 512];

  // A staging: MODE_OUT via DMA (8 chunks), MODE_Q via fp32 VGPR+cast
  const __bf16* gA0 = nullptr;
  const __bf16* gA1 = nullptr;
  __bf16* lA0 = &As[wave * 512];
  __bf16* lA1 = &As[(wave + 4) * 512];
  if constexpr (MODE == MODE_OUT) {
    const __bf16* Ab = (const __bf16*)Ain;
    gA0 = Ab + (size_t)(m0 + 16 * wave + srow) * K + scol;
    gA1 = Ab + (size_t)(m0 + 64 + 16 * wave + srow) * K + scol;
  }
  const float* Af = (const float*)Ain;

  v4f acc[4][2];
#pragma unroll
  for (int i = 0; i < 4; ++i)
#pragma unroll
    for (int j = 0; j < 2; ++j) acc[i][j] = (v4f){0.f, 0.f, 0.f, 0.f};

  for (int k0 = 0; k0 < K; k0 += 32) {
    load16_to_lds(gB0 + k0, lB0);
    if constexpr (MODE == MODE_OUT) {
      load16_to_lds(gA0 + k0, lA0);
      load16_to_lds(gA1 + k0, lA1);
    } else {
      // stage 128x32 from fp32: 1024 float4, 4 per thread, coalesced rows
#pragma unroll
      for (int p = 0; p < 4; ++p) {
        const int idx = p * 256 + t;
        const int row = idx >> 3, col = (idx & 7) * 4;
        float4 v = *(const float4*)&Af[(size_t)(m0 + row) * K + (k0 + col)];
        uint2 o;
        o.x = pack2bf(v.x, v.y);
        o.y = pack2bf(v.z, v.w);
        *(uint2*)&As[row * 32 + col] = o;
      }
    }
    __syncthreads();

    v8bf af[4], bfr[2];
#pragma unroll
    for (int i = 0; i < 4; ++i)
      af[i] = *(const v8bf*)&As[(wm + i * 16 + l15) * 32 + quad * 8];
#pragma unroll
    for (int j = 0; j < 2; ++j)
      bfr[j] = *(const v8bf*)&Bs[(wn + j * 16 + l15) * 32 + quad * 8];
#pragma unroll
    for (int i = 0; i < 4; ++i)
#pragma unroll
      for (int j = 0; j < 2; ++j)
        acc[i][j] = __builtin_amdgcn_mfma_f32_16x16x32_bf16(af[i], bfr[j], acc[i][j], 0, 0, 0);
    __syncthreads();
  }

#pragma unroll
  for (int i = 0; i < 4; ++i) {
#pragma unroll
    for (int j = 0; j < 2; ++j) {
#pragma unroll
      for (int r = 0; r < 4; ++r) {
        const int gm = m0 + wm + i * 16 + quad * 4 + r;
        const int gn = n0 + wn + j * 16 + l15;
        float v = acc[i][j][r];
        if constexpr (MODE == MODE_Q) {
          v += bias[gn];
          int idx = 0;
#pragma unroll
          for (int s = 128; s > 0; s >>= 1) {
            const int u = idx + s;
            if (cbs[u] <= v) idx = u;
          }
          float best = cbs[idx];
          if (idx < 255) {
            const float c1 = cbs[idx + 1];
            if (!(v - best <= c1 - v)) best = c1;
          }
          ((__bf16*)Cout)[(size_t)gm * N + gn] = (__bf16)best;
        } else {
          v += bias[gn];
          ((float*)Cout)[(size_t)gm * N + gn] = v;
        }
      }
    }
  }
}

extern "C" void kernel_launch(void* const* d_in, const int* in_sizes, int n_in,
                              void* d_out, int out_size, void* d_ws, size_t ws_size,
                              hipStream_t stream) {
  const float* x  = (const float*)d_in[0];
  const float* cb = (const float*)d_in[1];
  const float* w1 = (const float*)d_in[2];   // [4096,1024]
  const float* b1 = (const float*)d_in[3];
  const float* w2 = (const float*)d_in[4];   // [512,4096]
  const float* b2 = (const float*)d_in[5];
  const float* w3 = (const float*)d_in[6];   // [2048,512]
  const float* b3 = (const float*)d_in[7];
  const float* w4 = (const float*)d_in[8];   // [2048,2048]
  const float* b4 = (const float*)d_in[9];
  const float* w5 = (const float*)d_in[10];  // [512,2048]
  const float* b5 = (const float*)d_in[11];
  float* out = (float*)d_out;

  char* ws = (char*)d_ws;
  size_t off = 0;
  auto alloc = [&](size_t bytes) -> void* {
    void* p = ws + off;
    off = (off + bytes + 255) & ~(size_t)255;
    return p;
  };
  __bf16* w1T   = (__bf16*)alloc((size_t)DIN * H1dim * 2);
  __bf16* w4T   = (__bf16*)alloc((size_t)H3dim * H4dim * 2);
  __bf16* w3T   = (__bf16*)alloc((size_t)DOUT * H3dim * 2);
  __bf16* WaT   = (__bf16*)alloc((size_t)DOUT * DIN * 2);
  __bf16* WtT   = (__bf16*)alloc((size_t)DOUT * H3dim * 2);
  __bf16* WcT   = (__bf16*)alloc((size_t)DOUT * DOUT * 2);
  __bf16* q     = (__bf16*)alloc((size_t)Bdim * DOUT * 2);
  float*  ba    = (float*)alloc(DOUT * 4);
  float*  bc    = (float*)alloc(DOUT * 4);
  float*  part  = (float*)alloc((size_t)8 * DOUT * DIN * 4);

  // transposes (B operands for the folds)
  transpose_cast_kernel<<<dim3(DIN / 32, H1dim / 32), 256, 0, stream>>>(w1, w1T, H1dim, DIN);
  transpose_cast_kernel<<<dim3(H3dim / 32, H4dim / 32), 256, 0, stream>>>(w4, w4T, H4dim, H3dim);
  transpose_cast_kernel<<<dim3(DOUT / 32, H3dim / 32), 256, 0, stream>>>(w3, w3T, H3dim, DOUT);

  // fold 1: WaT = w2 @ w1, K=4096, S=8 (A = w2 fp32, cast in staging)
  gemm_bt_splitk_kernel<false><<<dim3(DOUT / 64, DIN / 64, 8), 256, 0, stream>>>(
      w2, w1T, part, DOUT, DIN, H1dim, H1dim / 8);
  reduce_cast_kernel<<<(DOUT * DIN / 4 + 255) / 256, 256, 0, stream>>>(
      part, WaT, DOUT * DIN / 4, 8);

  // fold 2: WtT = w5 @ w4, K=2048, S=4 (A = w5 fp32)
  gemm_bt_splitk_kernel<false><<<dim3(DOUT / 64, H3dim / 64, 4), 256, 0, stream>>>(
      w5, w4T, part, DOUT, H3dim, H4dim, H4dim / 4);
  reduce_cast_kernel<<<(DOUT * H3dim / 4 + 255) / 256, 256, 0, stream>>>(
      part, WtT, DOUT * H3dim / 4, 4);

  // folded biases (ba + bc in one dispatch; bc needs WtT)
  bias_kernel<<<256, 256, 0, stream>>>(b1, w2, b2, b3, WtT, b4, w5, b5, ba, bc);

  // fold 3: WcT = WtT @ w3, K=2048, S=8 (A = WtT bf16)
  gemm_bt_splitk_kernel<true><<<dim3(DOUT / 64, DOUT / 64, 8), 256, 0, stream>>>(
      WtT, w3T, part, DOUT, DOUT, H3dim, H3dim / 8);
  reduce_cast_kernel<<<(DOUT * DOUT / 4 + 255) / 256, 256, 0, stream>>>(
      part, WcT, DOUT * DOUT / 4, 8);

  // main: h2 = x@Wa + ba -> quantize -> q (A = x fp32, cast in staging)
  gemm_bt_kernel<MODE_Q><<<dim3(Bdim / 128, DOUT / 64), 256, 0, stream>>>(
      x, WaT, q, ba, cb, Bdim, DOUT, DIN);
  // out = q@Wc + bc
  gemm_bt_kernel<MODE_OUT><<<dim3(Bdim / 128, DOUT / 64), 256, 0, stream>>>(
      q, WcT, out, bc, nullptr, Bdim, DOUT, DOUT);
}